// Round 1
// baseline (3150.844 us; speedup 1.0000x reference)
//
#include <hip/hip_runtime.h>
#include <hip/hip_bf16.h>

// Model: 4 stacked LSTM layers (512->64, 64->64, 64->6, 6->6) + FC(6->6).
// B=64, T=1024. M = B*T = 65536 flattened rows.
//
// Strategy round 0 (correctness-first, fp32 everywhere):
//   per layer: xg = X @ W_ih^T + b   (parallel GEMM over M rows)
//              scan: sequential over T, one workgroup per batch element.

#define B_SZ 64
#define T_SZ 1024
#define M_SZ (B_SZ * T_SZ)

__device__ __forceinline__ float sigm_f(float x) {
    return 1.0f / (1.0f + __expf(-x));     // x->-inf: exp->inf -> 0  (no NaN)
}
__device__ __forceinline__ float tanh_f(float x) {
    return 2.0f / (1.0f + __expf(-2.0f * x)) - 1.0f;  // graceful at +/-inf
}

// ---------------- input-projection GEMM, G=256 gates, D in {512, 64} -------
// out[m, g] = bias[g] + sum_k X[m,k] * W[g,k]
template <int D>
__global__ __launch_bounds__(256) void gemm_ih(const float* __restrict__ X,
                                               const float* __restrict__ W,
                                               const float* __restrict__ bias,
                                               float* __restrict__ out) {
    const int m0 = blockIdx.x * 16;
    const int g  = threadIdx.x;                  // 0..255 = output gate
    __shared__ __align__(16) float As[16 * D];   // D=512 -> 32 KB
    for (int idx = g; idx < 16 * D; idx += 256) {
        As[idx] = X[(size_t)(m0 + idx / D) * D + (idx % D)];
    }
    __syncthreads();
    float acc[16];
    const float bg = bias[g];
#pragma unroll
    for (int m = 0; m < 16; ++m) acc[m] = bg;
    const float* Wg = W + (size_t)g * D;
    for (int k = 0; k < D; k += 4) {
        const float4 wv = *(const float4*)&Wg[k];
#pragma unroll
        for (int m = 0; m < 16; ++m) {
            const float4 av = *(const float4*)&As[m * D + k];
            acc[m] += av.x * wv.x + av.y * wv.y + av.z * wv.z + av.w * wv.w;
        }
    }
#pragma unroll
    for (int m = 0; m < 16; ++m) out[(size_t)(m0 + m) * 256 + g] = acc[m];
}

// ---------------- generic small GEMM (thread per output element) -----------
__global__ void gemm_naive(const float* __restrict__ X, const float* __restrict__ W,
                           const float* __restrict__ bias, float* __restrict__ out,
                           int M, int D, int G) {
    const int idx = blockIdx.x * 256 + threadIdx.x;
    if (idx >= M * G) return;
    const int m = idx / G, g = idx % G;
    float acc = bias[g];
    const float* xr = X + (size_t)m * D;
    const float* wr = W + (size_t)g * D;
    for (int k = 0; k < D; ++k) acc += xr[k] * wr[k];
    out[idx] = acc;
}

// ---------------- LSTM scan, H=64 (gates=256) -------------------------------
// One workgroup per batch element; thread g owns gate g (W_hh row in VGPRs).
__global__ __launch_bounds__(256) void scan64(const float* __restrict__ xg,
                                              const float* __restrict__ whh,
                                              float* __restrict__ hout) {
    const int b = blockIdx.x;
    const int g = threadIdx.x;          // 0..255
    __shared__ __align__(16) float h_s[64];
    __shared__ float gates_s[256];
    float w[64];
#pragma unroll
    for (int k = 0; k < 64; ++k) w[k] = whh[g * 64 + k];
    float c = 0.0f;
    if (g < 64) h_s[g] = 0.0f;
    __syncthreads();

    const float* xgb = xg + (size_t)b * T_SZ * 256;
    float xv = xgb[g];                  // prefetch t=0
    for (int t = 0; t < T_SZ; ++t) {
        float xv_next = (t + 1 < T_SZ) ? xgb[(size_t)(t + 1) * 256 + g] : 0.0f;
        float acc = xv;
#pragma unroll
        for (int k = 0; k < 64; k += 4) {
            const float4 hv = *(const float4*)&h_s[k];   // same-addr broadcast
            acc += w[k] * hv.x + w[k + 1] * hv.y + w[k + 2] * hv.z + w[k + 3] * hv.w;
        }
        const float val = ((g >> 6) == 2) ? tanh_f(acc) : sigm_f(acc);
        gates_s[g] = val;
        __syncthreads();
        if (g < 64) {
            const float iv = gates_s[g];
            const float fv = gates_s[64 + g];
            const float gv = gates_s[128 + g];
            const float ov = gates_s[192 + g];
            c = fv * c + iv * gv;
            const float hh = ov * tanh_f(c);
            h_s[g] = hh;
            hout[((size_t)b * T_SZ + t) * 64 + g] = hh;
        }
        __syncthreads();
        xv = xv_next;
    }
}

// ---------------- LSTM scan, H=6 (gates=24) ---------------------------------
__global__ __launch_bounds__(64) void scan6(const float* __restrict__ xg,
                                            const float* __restrict__ whh,
                                            float* __restrict__ hout) {
    const int b = blockIdx.x;
    const int g = threadIdx.x;          // 0..63, gates live in g<24
    __shared__ float h_s[8];
    __shared__ float gates_s[24];
    float w[6];
#pragma unroll
    for (int k = 0; k < 6; ++k) w[k] = 0.0f;
    if (g < 24) {
#pragma unroll
        for (int k = 0; k < 6; ++k) w[k] = whh[g * 6 + k];
    }
    float c = 0.0f;
    if (g < 6) h_s[g] = 0.0f;
    __syncthreads();

    const float* xgb = xg + (size_t)b * T_SZ * 24;
    for (int t = 0; t < T_SZ; ++t) {
        float acc = (g < 24) ? xgb[(size_t)t * 24 + g] : 0.0f;
#pragma unroll
        for (int k = 0; k < 6; ++k) acc += w[k] * h_s[k];
        const float val = ((g / 6) == 2) ? tanh_f(acc) : sigm_f(acc);
        if (g < 24) gates_s[g] = val;
        __syncthreads();
        if (g < 6) {
            const float iv = gates_s[g];
            const float fv = gates_s[6 + g];
            const float gv = gates_s[12 + g];
            const float ov = gates_s[18 + g];
            c = fv * c + iv * gv;
            const float hh = ov * tanh_f(c);
            h_s[g] = hh;
            hout[((size_t)b * T_SZ + t) * 6 + g] = hh;
        }
        __syncthreads();
    }
}

extern "C" void kernel_launch(void* const* d_in, const int* in_sizes, int n_in,
                              void* d_out, int out_size, void* d_ws, size_t ws_size,
                              hipStream_t stream) {
    const float* x      = (const float*)d_in[0];   // [64,1024,512]
    const float* w1_ih0 = (const float*)d_in[1];   // [256,512]
    const float* w1_hh0 = (const float*)d_in[2];   // [256,64]
    const float* b1_0   = (const float*)d_in[3];   // [256]
    const float* w1_ih1 = (const float*)d_in[4];   // [256,64]
    const float* w1_hh1 = (const float*)d_in[5];   // [256,64]
    const float* b1_1   = (const float*)d_in[6];   // [256]
    const float* w2_ih0 = (const float*)d_in[7];   // [24,64]
    const float* w2_hh0 = (const float*)d_in[8];   // [24,6]
    const float* b2_0   = (const float*)d_in[9];   // [24]
    const float* w2_ih1 = (const float*)d_in[10];  // [24,6]
    const float* w2_hh1 = (const float*)d_in[11];  // [24,6]
    const float* b2_1   = (const float*)d_in[12];  // [24]
    const float* fc_w   = (const float*)d_in[13];  // [6,6]
    const float* fc_b   = (const float*)d_in[14];  // [6]
    float* out = (float*)d_out;                    // [64,1024,6]

    const int M = M_SZ;
    float* xg = (float*)d_ws;                  // M*256 floats (67 MB)
    float* hA = xg + (size_t)M * 256;          // M*64
    float* hB = hA + (size_t)M * 64;           // M*64

    // L1: 512 -> 64
    gemm_ih<512><<<M / 16, 256, 0, stream>>>(x, w1_ih0, b1_0, xg);
    scan64<<<B_SZ, 256, 0, stream>>>(xg, w1_hh0, hA);
    // L2: 64 -> 64
    gemm_ih<64><<<M / 16, 256, 0, stream>>>(hA, w1_ih1, b1_1, xg);
    scan64<<<B_SZ, 256, 0, stream>>>(xg, w1_hh1, hB);
    // L3: 64 -> 6
    gemm_naive<<<(M * 24 + 255) / 256, 256, 0, stream>>>(hB, w2_ih0, b2_0, xg, M, 64, 24);
    scan6<<<B_SZ, 64, 0, stream>>>(xg, w2_hh0, hA);      // hA := h3 [M,6]
    // L4: 6 -> 6
    gemm_naive<<<(M * 24 + 255) / 256, 256, 0, stream>>>(hA, w2_ih1, b2_1, xg, M, 6, 24);
    scan6<<<B_SZ, 64, 0, stream>>>(xg, w2_hh1, hB);      // hB := h4 [M,6]
    // FC: 6 -> 6
    gemm_naive<<<(M * 6) / 256, 256, 0, stream>>>(hB, fc_w, fc_b, out, M, 6, 6);
}